// Round 19
// baseline (540.311 us; speedup 1.0000x reference)
//
#include <hip/hip_runtime.h>
#include <math.h>

typedef unsigned short u16;
typedef u16 u16x8 __attribute__((ext_vector_type(8)));
typedef __bf16 bf16x8 __attribute__((ext_vector_type(8)));
typedef float f32x4 __attribute__((ext_vector_type(4)));

#define HID 200
#define G4H 800
#define TLEN 128
#define LATENT 128
#define NCODES 1024
#define DIN 768
#define DCOND 1536
#define NB 256
#define MROWS (NB * TLEN)
#define LDG 896
#define LDH1 256
#define LDH2 512
#define NOUT 768

#define WSCL 400.0f
#define HSCL 127.0f
#define ISCL (1.0f / (WSCL * HSCL))
#define W4_UINT4 (12 * 800)          // k 0..191, i8-packed, [jb][row] uint4
#define W4_BYTES (W4_UINT4 * 16)     // 153600
#define NTHR 640

__device__ __forceinline__ u16 f2b(float f) {
  union { float f; unsigned u; } v; v.f = f;
  unsigned r = v.u + 0x7fffu + ((v.u >> 16) & 1u);
  return (u16)(r >> 16);
}
__device__ __forceinline__ float b2f(u16 h) {
  union { unsigned u; float f; } v; v.u = ((unsigned)h) << 16;
  return v.f;
}
__device__ __forceinline__ float sigf(float x) { return 1.f / (1.f + __expf(-x)); }
__device__ __forceinline__ float tanh_fast(float x) {
  return 1.f - 2.f / (__expf(2.f * x) + 1.f);
}

__device__ __forceinline__ int dot4(unsigned a, unsigned b, int c) {
#if __has_builtin(__builtin_amdgcn_sdot4)
  return __builtin_amdgcn_sdot4((int)a, (int)b, c, false);
#else
  int s = c;
  s += (int)(signed char)(a) * (int)(signed char)(b);
  s += (int)(signed char)(a >> 8) * (int)(signed char)(b >> 8);
  s += (int)(signed char)(a >> 16) * (int)(signed char)(b >> 16);
  s += (int)(signed char)(a >> 24) * (int)(signed char)(b >> 24);
  return s;
#endif
}

// async global->LDS, 16B per lane
__device__ __forceinline__ void gl16(const void* g, void* l) {
  __builtin_amdgcn_global_load_lds(
      (const __attribute__((address_space(1))) void*)g,
      (__attribute__((address_space(3))) void*)l, 16, 0, 0);
}

__device__ __forceinline__ unsigned cvtpk(float a, float b) {
  unsigned r;
  asm("v_cvt_pk_bf16_f32 %0, %1, %2" : "=v"(r) : "v"(a), "v"(b));
  return r;
}

// LDS-ordering-only barrier: global prefetch loads stay in flight (no vmcnt drain)
__device__ __forceinline__ void bar_lds() {
  asm volatile("s_waitcnt lgkmcnt(0)\n\ts_barrier" ::: "memory");
}

// ---------------- weight convert + pad ----------------
__global__ void cvt_pad(const float* __restrict__ src, u16* __restrict__ dst,
                        int nr, int nc, int lds, int col0, int NRp, int KP) {
  int i = blockIdx.x * blockDim.x + threadIdx.x;
  if (i >= NRp * KP) return;
  int r = i / KP, c = i - r * KP;
  float v = (r < nr && c < nc) ? src[(size_t)r * lds + col0 + c] : 0.f;
  dst[i] = f2b(v);
}

__global__ void pad_f32(const float* __restrict__ src, float* __restrict__ dst,
                        int n, int npad) {
  int i = blockIdx.x * blockDim.x + threadIdx.x;
  if (i < npad) dst[i] = (i < n) ? src[i] : 0.f;
}

// W_hh [800][200] f32 -> i8 (x400 scale):
//   k 0..191  -> W4 dword index (jb*800 + row)*4 + word   (uint4 per [jb][row])
//   k 192..199-> Wreg[u*8 + g*2 + d] for row = g*200+u
// biasc[col<896] = b_ih+b_hh (0-padded) for the gates-GEMM epilogue.
__global__ void pack_whh_i8(const float* __restrict__ Whh, unsigned* __restrict__ W4,
                            unsigned* __restrict__ Wreg,
                            const float* __restrict__ b_ih, const float* __restrict__ b_hh,
                            float* __restrict__ biasc) {
  int i = blockIdx.x * blockDim.x + threadIdx.x;
  if (i < 800 * 50) {
    int row = i / 50, dw = i - row * 50;
    unsigned d = 0;
#pragma unroll
    for (int e = 0; e < 4; ++e) {
      int k = dw * 4 + e;
      float w = Whh[(size_t)row * HID + k] * WSCL;
      int q = (int)lrintf(w);
      q = q > 127 ? 127 : (q < -127 ? -127 : q);
      d |= ((unsigned)(q & 0xFF)) << (8 * e);
    }
    if (dw < 48) {
      W4[((dw >> 2) * 800 + row) * 4 + (dw & 3)] = d;
    } else {  // dw in {48,49}: k 192..199
      int g = row / 200, u = row - g * 200;
      Wreg[u * 8 + g * 2 + (dw - 48)] = d;
    }
  }
  if (i < LDG) biasc[i] = (i < G4H) ? (b_ih[i] + b_hh[i]) : 0.f;
}

// ---------------- bf16 MFMA GEMM: C[M,N] = A[M,K] * B[N,K]^T (+epilogue) ----------------
// 1D grid + chunked XCD swizzle (T1, m157): logical id = (bid&7)*(nwg/8)+(bid>>3).
enum { EPI_GATES = 0, EPI_H1 = 1, EPI_H2 = 2, EPI_OUT = 3 };

__device__ __forceinline__ f32x4 mfma16(bf16x8 a, bf16x8 b, f32x4 c) {
  return __builtin_amdgcn_mfma_f32_16x16x32_bf16(a, b, c, 0, 0, 0);
}

template<bool AF32, int EPI>
__global__ __launch_bounds__(256) void gemm_bf16(
    const void* __restrict__ Ap, const u16* __restrict__ Bp,
    void* __restrict__ Cp, int K, int ldc, const float* __restrict__ bias, int nx) {
  __shared__ __attribute__((aligned(16))) char AsRaw[AF32 ? 128 * 32 * 4 : 128 * 32 * 2];
  __shared__ __attribute__((aligned(16))) u16 Bs[128 * 32];
  float* Asf = (float*)AsRaw;
  u16* As16 = (u16*)AsRaw;

  const int t = threadIdx.x;
  const int nwg = gridDim.x;
  const int bid = blockIdx.x;
  const int lid = (bid & 7) * (nwg >> 3) + (bid >> 3);   // chunked XCD swizzle
  const int tileN = (lid % nx) * 128;
  const int tileM = (lid / nx) * 128;
  const int l = t & 63;
  const int w = t >> 6;
  const int wr = (w >> 1) * 64;
  const int wc = (w & 1) * 64;
  const int fr = l & 15;
  const int fg = l >> 4;

  const u16* bsrc[2];
  u16* bdst[2];
#pragma unroll
  for (int j = 0; j < 2; ++j) {
    int tb = w * 1024 + j * 4096 + (t & 63) * 16;
    int row = tb >> 6, gd = (tb >> 4) & 3;
    bsrc[j] = Bp + (size_t)(tileN + row) * K + ((gd ^ ((row >> 1) & 3)) << 3);
    bdst[j] = Bs + w * 512 + j * 2048;
  }
  const float* asrcF[4];
  float* adstF[4];
  const u16* asrcH[2];
  u16* adstH[2];
  if constexpr (AF32) {
#pragma unroll
    for (int j = 0; j < 4; ++j) {
      int tb = w * 1024 + j * 4096 + (t & 63) * 16;
      int row = tb >> 7, gd = (tb >> 4) & 7;
      asrcF[j] = (const float*)Ap + (size_t)(tileM + row) * K + ((gd ^ (row & 7)) << 2);
      adstF[j] = Asf + w * 256 + j * 1024;
    }
  } else {
#pragma unroll
    for (int j = 0; j < 2; ++j) {
      int tb = w * 1024 + j * 4096 + (t & 63) * 16;
      int row = tb >> 6, gd = (tb >> 4) & 3;
      asrcH[j] = (const u16*)Ap + (size_t)(tileM + row) * K + ((gd ^ ((row >> 1) & 3)) << 3);
      adstH[j] = As16 + w * 512 + j * 2048;
    }
  }

  f32x4 acc[4][4];
#pragma unroll
  for (int m = 0; m < 4; ++m)
#pragma unroll
    for (int n = 0; n < 4; ++n) {
      f32x4 z = {0.f, 0.f, 0.f, 0.f};
      acc[m][n] = z;
    }

  for (int k0 = 0; k0 < K; k0 += 32) {
#pragma unroll
    for (int j = 0; j < 2; ++j) { gl16(bsrc[j], bdst[j]); bsrc[j] += 32; }
    if constexpr (AF32) {
#pragma unroll
      for (int j = 0; j < 4; ++j) { gl16(asrcF[j], adstF[j]); asrcF[j] += 32; }
    } else {
#pragma unroll
      for (int j = 0; j < 2; ++j) { gl16(asrcH[j], adstH[j]); asrcH[j] += 32; }
    }
    __syncthreads();

    bf16x8 av[4], bv[4];
#pragma unroll
    for (int m = 0; m < 4; ++m) {
      const int row = wr + m * 16 + fr;
      if constexpr (AF32) {
        const int g0 = (2 * fg) ^ (row & 7);
        const int g1 = (2 * fg + 1) ^ (row & 7);
        float4 p0 = *(const float4*)(Asf + row * 32 + g0 * 4);
        float4 p1 = *(const float4*)(Asf + row * 32 + g1 * 4);
        uint4 u;
        u.x = cvtpk(p0.x, p0.y); u.y = cvtpk(p0.z, p0.w);
        u.z = cvtpk(p1.x, p1.y); u.w = cvtpk(p1.z, p1.w);
        av[m] = __builtin_bit_cast(bf16x8, u);
      } else {
        const int g = fg ^ ((row >> 1) & 3);
        av[m] = __builtin_bit_cast(bf16x8, *(const u16x8*)(As16 + row * 32 + g * 8));
      }
    }
#pragma unroll
    for (int n = 0; n < 4; ++n) {
      const int row = wc + n * 16 + fr;
      const int g = fg ^ ((row >> 1) & 3);
      bv[n] = __builtin_bit_cast(bf16x8, *(const u16x8*)(Bs + row * 32 + g * 8));
    }
#pragma unroll
    for (int m = 0; m < 4; ++m)
#pragma unroll
      for (int n = 0; n < 4; ++n)
        acc[m][n] = mfma16(av[m], bv[n], acc[m][n]);
    __syncthreads();
  }

#pragma unroll
  for (int m = 0; m < 4; ++m) {
#pragma unroll
    for (int n = 0; n < 4; ++n) {
      const int gcol = tileN + wc + n * 16 + fr;
      const int growb = tileM + wr + m * 16 + fg * 4;
#pragma unroll
      for (int r = 0; r < 4; ++r) {
        const int grow = growb + r;
        float v = acc[m][n][r];
        if constexpr (EPI == EPI_GATES) {
          v += bias[gcol];   // b_ih + b_hh folded here
          ((u16*)Cp)[(size_t)grow * ldc + gcol] = f2b(v);
        } else if constexpr (EPI == EPI_H1) {
          v += bias[(grow >> 7) * 256 + gcol];
          v = fmaxf(v, 0.f);
          ((u16*)Cp)[(size_t)grow * ldc + gcol] = f2b(v);
        } else if constexpr (EPI == EPI_H2) {
          v += bias[gcol];
          v = fmaxf(v, 0.f);
          ((u16*)Cp)[(size_t)grow * ldc + gcol] = f2b(v);
        } else {
          v += bias[gcol];
          ((float*)Cp)[(size_t)grow * ldc + gcol] = sigf(v);
        }
      }
    }
  }
}

// ---------------- fused LSTM scan + encoder + VQ + p1 ----------------
// 640 threads (10 waves), one block per batch. W_hh i8 in LDS ([jb][row]
// uint4) + tail dwords in kh2 regs. 3-way k-split + REDUNDANT ACTIVATION
// (R18 intent, LDS budget fixed): all kh groups write partials sh_p[kh][u],
// all act threads read all three in fixed order (bit-identical floats) and
// replicate the activation with their own c; only kh0 writes h.
// LDS budget: sh_hq 416B + union 9600B static; union holds sh_p during the
// scan and hf/ze/zq/rd/ri afterwards (sh_p dead post-loop). 10,016 static +
// 153,600 dynamic <= 163,840.
__global__ __launch_bounds__(NTHR) void lstm_enc(
    const u16* __restrict__ gates, const uint4* __restrict__ W4g,
    const uint4* __restrict__ WregG,
    const float* __restrict__ Wenc, const float* __restrict__ b_enc,
    const float* __restrict__ emb, const float* __restrict__ W1,
    const float* __restrict__ b1, const float* __restrict__ noise,
    float* __restrict__ p1) {
  extern __shared__ __attribute__((aligned(16))) char dynsm[];
  uint4* W4 = (uint4*)dynsm;                       // [12*800] uint4 (i8)
  __shared__ __attribute__((aligned(16))) unsigned sh_hq[2][52];  // h i8, dbuf, pad 0
  __shared__ __attribute__((aligned(16))) char sh_un[3 * 200 * 16];  // 9600B union
  int (*sh_p)[200][4] = (int(*)[200][4])sh_un;   // scan: [3][200][4]
  float* sh_hf = (float*)sh_un;                  // post-scan: [200]   @0
  float* sh_ze = (float*)(sh_un + 800);          // [128]  @800
  float* sh_zq = (float*)(sh_un + 1312);         // [128]  @1312
  float* sh_rd = (float*)(sh_un + 1824);         // [640]  @1824
  int*   sh_ri = (int*)(sh_un + 4384);           // [640]  @4384 (ends 6944)
  const int r = threadIdx.x;
  const int b = blockIdx.x;
  const bool act = (r < 600);
  const int kh = r / 200;          // 0,1,2 (3 for idle tail)
  const int u = r - kh * 200;
  const bool lo = (kh == 0);

  // stage W4 into LDS (9600 uint4, coalesced; L2-resident source)
  for (int i = r; i < W4_UINT4; i += NTHR) W4[i] = W4g[i];
  uint4 wt0 = {0, 0, 0, 0}, wt1 = {0, 0, 0, 0};
  if (kh == 2) { wt0 = WregG[u * 2]; wt1 = WregG[u * 2 + 1]; }
  if (r < 52) { sh_hq[0][r] = 0; sh_hq[1][r] = 0; }
  float c = 0.f, hlast = 0.f;
  const u16* gp = gates + (size_t)b * TLEN * LDG + u;
  float gv0 = 0.f, gv1 = 0.f, gv2 = 0.f, gv3 = 0.f;
  if (act) {
    gv0 = b2f(gp[0]); gv1 = b2f(gp[200]);
    gv2 = b2f(gp[400]); gv3 = b2f(gp[600]);
  }
  __syncthreads();   // full drain: W4 staging (global_load_lds) resident

  for (int t = 0; t < TLEN; ++t) {
    gp += LDG;
    float gn0 = 0.f, gn1 = 0.f, gn2 = 0.f, gn3 = 0.f;
    if (act && t + 1 < TLEN) {
      gn0 = b2f(gp[0]); gn1 = b2f(gp[200]);
      gn2 = b2f(gp[400]); gn3 = b2f(gp[600]);
    }
    const int cur = t & 1, nxt = cur ^ 1;

    if (act) {
      int a0 = 0, a1 = 0, a2 = 0, a3 = 0;
      unsigned hd[16];
#pragma unroll
      for (int j = 0; j < 4; ++j) {
        uint4 v = ((const uint4*)sh_hq[cur])[kh * 4 + j];
        hd[4 * j + 0] = v.x; hd[4 * j + 1] = v.y;
        hd[4 * j + 2] = v.z; hd[4 * j + 3] = v.w;
      }
#pragma unroll
      for (int j = 0; j < 4; ++j) {
        const int jb = kh * 4 + j;
        uint4 w0 = W4[jb * 800 + u];
        uint4 w1 = W4[jb * 800 + 200 + u];
        uint4 w2 = W4[jb * 800 + 400 + u];
        uint4 w3 = W4[jb * 800 + 600 + u];
#pragma unroll
        for (int e = 0; e < 4; ++e) {
          unsigned h = hd[j * 4 + e];
          a0 = dot4((&w0.x)[e], h, a0);
          a1 = dot4((&w1.x)[e], h, a1);
          a2 = dot4((&w2.x)[e], h, a2);
          a3 = dot4((&w3.x)[e], h, a3);
        }
      }
      if (kh == 2) {
        // tail k 192..199 from registers
        uint2 ht = *(const uint2*)&sh_hq[cur][48];
        a0 = dot4(wt0.x, ht.x, a0); a0 = dot4(wt0.y, ht.y, a0);
        a1 = dot4(wt0.z, ht.x, a1); a1 = dot4(wt0.w, ht.y, a1);
        a2 = dot4(wt1.x, ht.x, a2); a2 = dot4(wt1.y, ht.y, a2);
        a3 = dot4(wt1.z, ht.x, a3); a3 = dot4(wt1.w, ht.y, a3);
      }
      int4 pv; pv.x = a0; pv.y = a1; pv.z = a2; pv.w = a3;
      *(int4*)&sh_p[kh][u][0] = pv;
    }
    bar_lds();   // all partials visible; gate prefetch stays in flight
    if (act) {
      int4 q0 = *(const int4*)&sh_p[0][u][0];
      int4 q1 = *(const int4*)&sh_p[1][u][0];
      int4 q2 = *(const int4*)&sh_p[2][u][0];
      float gi = gv0 + (float)(q0.x + q1.x + q2.x) * ISCL;
      float gf = gv1 + (float)(q0.y + q1.y + q2.y) * ISCL;
      float gg = gv2 + (float)(q0.z + q1.z + q2.z) * ISCL;
      float go = gv3 + (float)(q0.w + q1.w + q2.w) * ISCL;
      c = sigf(gf) * c + sigf(gi) * tanh_fast(gg);
      hlast = sigf(go) * tanh_fast(c);
      if (lo) ((char*)sh_hq[nxt])[u] = (char)__float2int_rn(hlast * HSCL);
    }
    bar_lds();   // h(t+1) visible; sh_p free for reuse
    gv0 = gn0; gv1 = gn1; gv2 = gn2; gv3 = gn3;
  }

  __syncthreads();   // sh_p fully dead before union reuse
  if (lo) sh_hf[u] = hlast;
  __syncthreads();

  // encoder: z_e = h @ Wenc^T + b_enc
  if (r < LATENT) {
    float z = b_enc[r];
#pragma unroll 4
    for (int k = 0; k < HID; ++k) z = fmaf(Wenc[(size_t)r * HID + k], sh_hf[k], z);
    sh_ze[r] = z;
  }
  __syncthreads();

  // VQ: argmin_k ||e_k||^2 - 2 z_e . e_k
  float best = INFINITY; int bi = 0;
  for (int k = r; k < NCODES; k += NTHR) {
    float d = 0.f;
#pragma unroll
    for (int q = 0; q < LATENT / 4; ++q) {
      float4 e = *(const float4*)&emb[(size_t)k * LATENT + q * 4];
      float4 z = *(const float4*)&sh_ze[q * 4];
      d += e.x * (e.x - 2.f * z.x) + e.y * (e.y - 2.f * z.y)
         + e.z * (e.z - 2.f * z.z) + e.w * (e.w - 2.f * z.w);
    }
    if (d < best) { best = d; bi = k; }
  }
  sh_rd[r] = best; sh_ri[r] = bi;
  __syncthreads();
  for (int s = 512; s > 0; s >>= 1) {
    if (r < s && r + s < NTHR) {
      float od = sh_rd[r + s]; int oi = sh_ri[r + s];
      if (od < sh_rd[r] || (od == sh_rd[r] && oi < sh_ri[r])) { sh_rd[r] = od; sh_ri[r] = oi; }
    }
    __syncthreads();
  }
  const int kmin = sh_ri[0];
  if (r < LATENT) sh_zq[r] = emb[(size_t)kmin * LATENT + r];
  __syncthreads();

  // p1[b][j] = b1 + W1[:,0:128].zq + W1[:,1664:2432].noise  (pad cols 200..255 = 0)
  if (r < 256) {
    float v = 0.f;
    if (r < HID) {
      v = b1[r];
      const float* wrow = W1 + (size_t)r * 2432;
#pragma unroll 4
      for (int d = 0; d < LATENT; ++d) v = fmaf(wrow[d], sh_zq[d], v);
      const float* nz = noise + (size_t)b * DIN;
#pragma unroll 4
      for (int d = 0; d < DIN; ++d) v = fmaf(wrow[1664 + d], nz[d], v);
    }
    p1[b * 256 + r] = v;
  }
}

// ---------------- host ----------------
extern "C" void kernel_launch(void* const* d_in, const int* in_sizes, int n_in,
                              void* d_out, int out_size, void* d_ws, size_t ws_size,
                              hipStream_t stream) {
  const float* x     = (const float*)d_in[0];
  const float* cond  = (const float*)d_in[1];
  const float* noise = (const float*)d_in[2];
  const float* W_ih  = (const float*)d_in[3];
  const float* W_hh  = (const float*)d_in[4];
  const float* b_ih  = (const float*)d_in[5];
  const float* b_hh  = (const float*)d_in[6];
  const float* W_enc = (const float*)d_in[7];
  const float* b_enc = (const float*)d_in[8];
  const float* emb   = (const float*)d_in[9];
  const float* W1    = (const float*)d_in[10];
  const float* b1    = (const float*)d_in[11];
  const float* W2    = (const float*)d_in[12];
  const float* b2    = (const float*)d_in[13];
  const float* W3    = (const float*)d_in[14];
  const float* b3    = (const float*)d_in[15];

  char* ws = (char*)d_ws;
  size_t off = 0;
  auto alloc = [&](size_t bytes) -> void* {
    void* p = ws + off; off += (bytes + 255) & ~(size_t)255; return p;
  };
  u16*      W_ihb = (u16*)alloc((size_t)896 * 768 * 2);
  u16*      W1cb  = (u16*)alloc((size_t)256 * 1536 * 2);
  u16*      W2b   = (u16*)alloc((size_t)512 * 256 * 2);
  u16*      W3b   = (u16*)alloc((size_t)768 * 512 * 2);
  float*    b2p   = (float*)alloc(512 * 4);
  unsigned* W4    = (unsigned*)alloc((size_t)W4_BYTES);
  unsigned* Wreg  = (unsigned*)alloc((size_t)200 * 8 * 4);
  float*    biasc = (float*)alloc(LDG * 4);
  u16*      gates = (u16*)alloc((size_t)MROWS * LDG * 2);
  float*    p1    = (float*)alloc(256 * 256 * 4);
  u16*      h1    = (u16*)alloc((size_t)MROWS * LDH1 * 2);
  u16*      h2    = (u16*)alloc((size_t)MROWS * LDH2 * 2);

  cvt_pad<<<dim3((896 * 768 + 255) / 256), 256, 0, stream>>>(W_ih, W_ihb, 800, 768, 768, 0, 896, 768);
  cvt_pad<<<dim3((256 * 1536 + 255) / 256), 256, 0, stream>>>(W1, W1cb, 200, 1536, 2432, 128, 256, 1536);
  cvt_pad<<<dim3((512 * 256 + 255) / 256), 256, 0, stream>>>(W2, W2b, 400, 200, 200, 0, 512, 256);
  cvt_pad<<<dim3((768 * 512 + 255) / 256), 256, 0, stream>>>(W3, W3b, 768, 400, 400, 0, 768, 512);
  pad_f32<<<dim3(2), 256, 0, stream>>>(b2, b2p, 400, 512);
  pack_whh_i8<<<dim3((800 * 50 + 255) / 256), 256, 0, stream>>>(W_hh, W4, Wreg, b_ih, b_hh, biasc);

  // gates = x @ W_ih^T + (b_ih + b_hh), bf16 out, ld 896  (1792 blocks, %8==0)
  gemm_bf16<true, EPI_GATES><<<dim3((LDG / 128) * (MROWS / 128)), 256, 0, stream>>>(
      x, W_ihb, gates, 768, LDG, biasc, LDG / 128);

  // LSTM scan + encoder + VQ + p1 (W_hh in dynamic LDS, i8; 640 thr, 3-way k-split)
  static bool attr_set = false;
  if (!attr_set) {
    (void)hipFuncSetAttribute((const void*)lstm_enc,
                              hipFuncAttributeMaxDynamicSharedMemorySize, W4_BYTES);
    attr_set = true;
  }
  lstm_enc<<<dim3(NB), NTHR, W4_BYTES, stream>>>(gates, (const uint4*)W4, (const uint4*)Wreg,
                                                 W_enc, b_enc, emb, W1, b1, noise, p1);

  // h1 = relu(cond @ W1c^T + p1[b])   (512 blocks)
  gemm_bf16<true, EPI_H1><<<dim3((LDH1 / 128) * (MROWS / 128)), 256, 0, stream>>>(
      cond, W1cb, h1, DCOND, LDH1, p1, LDH1 / 128);
  // h2 = relu(h1 @ W2^T + b2)   (1024 blocks)
  gemm_bf16<false, EPI_H2><<<dim3((LDH2 / 128) * (MROWS / 128)), 256, 0, stream>>>(
      h1, W2b, h2, LDH1, LDH2, b2p, LDH2 / 128);
  // out = sigmoid(h2 @ W3^T + b3)   (1536 blocks)
  gemm_bf16<false, EPI_OUT><<<dim3((NOUT / 128) * (MROWS / 128)), 256, 0, stream>>>(
      h2, W3b, (float*)d_out, LDH2, NOUT, b3, NOUT / 128);
}

// Round 20
// 475.943 us; speedup vs baseline: 1.1352x; 1.1352x over previous
//
#include <hip/hip_runtime.h>
#include <math.h>

typedef unsigned short u16;
typedef u16 u16x8 __attribute__((ext_vector_type(8)));
typedef __bf16 bf16x8 __attribute__((ext_vector_type(8)));
typedef float f32x4 __attribute__((ext_vector_type(4)));

#define HID 200
#define G4H 800
#define TLEN 128
#define LATENT 128
#define NCODES 1024
#define DIN 768
#define DCOND 1536
#define NB 256
#define MROWS (NB * TLEN)
#define LDG 896
#define LDH1 256
#define LDH2 512
#define NOUT 768

#define WSCL 400.0f
#define HSCL 127.0f
#define ISCL (1.0f / (WSCL * HSCL))
#define W4_UINT4 (12 * 800)          // k 0..191, i8-packed, [jb][row] uint4
#define W4_BYTES (W4_UINT4 * 16)     // 153600
#define NTHR 640

__device__ __forceinline__ u16 f2b(float f) {
  union { float f; unsigned u; } v; v.f = f;
  unsigned r = v.u + 0x7fffu + ((v.u >> 16) & 1u);
  return (u16)(r >> 16);
}
__device__ __forceinline__ float b2f(u16 h) {
  union { unsigned u; float f; } v; v.u = ((unsigned)h) << 16;
  return v.f;
}
__device__ __forceinline__ float sigf(float x) { return 1.f / (1.f + __expf(-x)); }
__device__ __forceinline__ float tanh_fast(float x) {
  return 1.f - 2.f / (__expf(2.f * x) + 1.f);
}

__device__ __forceinline__ int dot4(unsigned a, unsigned b, int c) {
#if __has_builtin(__builtin_amdgcn_sdot4)
  return __builtin_amdgcn_sdot4((int)a, (int)b, c, false);
#else
  int s = c;
  s += (int)(signed char)(a) * (int)(signed char)(b);
  s += (int)(signed char)(a >> 8) * (int)(signed char)(b >> 8);
  s += (int)(signed char)(a >> 16) * (int)(signed char)(b >> 16);
  s += (int)(signed char)(a >> 24) * (int)(signed char)(b >> 24);
  return s;
#endif
}

// async global->LDS, 16B per lane
__device__ __forceinline__ void gl16(const void* g, void* l) {
  __builtin_amdgcn_global_load_lds(
      (const __attribute__((address_space(1))) void*)g,
      (__attribute__((address_space(3))) void*)l, 16, 0, 0);
}

__device__ __forceinline__ unsigned cvtpk(float a, float b) {
  unsigned r;
  asm("v_cvt_pk_bf16_f32 %0, %1, %2" : "=v"(r) : "v"(a), "v"(b));
  return r;
}

// LDS-ordering-only barrier: global prefetch loads stay in flight (no vmcnt drain)
__device__ __forceinline__ void bar_lds() {
  asm volatile("s_waitcnt lgkmcnt(0)\n\ts_barrier" ::: "memory");
}

// ---------------- weight convert + pad ----------------
__global__ void cvt_pad(const float* __restrict__ src, u16* __restrict__ dst,
                        int nr, int nc, int lds, int col0, int NRp, int KP) {
  int i = blockIdx.x * blockDim.x + threadIdx.x;
  if (i >= NRp * KP) return;
  int r = i / KP, c = i - r * KP;
  float v = (r < nr && c < nc) ? src[(size_t)r * lds + col0 + c] : 0.f;
  dst[i] = f2b(v);
}

__global__ void pad_f32(const float* __restrict__ src, float* __restrict__ dst,
                        int n, int npad) {
  int i = blockIdx.x * blockDim.x + threadIdx.x;
  if (i < npad) dst[i] = (i < n) ? src[i] : 0.f;
}

// W_hh [800][200] f32 -> i8 (x400 scale):
//   k 0..191  -> W4 dword index (jb*800 + row)*4 + word   (uint4 per [jb][row])
//   k 192..199-> Wreg[u*8 + g*2 + d] for row = g*200+u
// biasc[col<896] = b_ih+b_hh (0-padded) for the gates-GEMM epilogue.
__global__ void pack_whh_i8(const float* __restrict__ Whh, unsigned* __restrict__ W4,
                            unsigned* __restrict__ Wreg,
                            const float* __restrict__ b_ih, const float* __restrict__ b_hh,
                            float* __restrict__ biasc) {
  int i = blockIdx.x * blockDim.x + threadIdx.x;
  if (i < 800 * 50) {
    int row = i / 50, dw = i - row * 50;
    unsigned d = 0;
#pragma unroll
    for (int e = 0; e < 4; ++e) {
      int k = dw * 4 + e;
      float w = Whh[(size_t)row * HID + k] * WSCL;
      int q = (int)lrintf(w);
      q = q > 127 ? 127 : (q < -127 ? -127 : q);
      d |= ((unsigned)(q & 0xFF)) << (8 * e);
    }
    if (dw < 48) {
      W4[((dw >> 2) * 800 + row) * 4 + (dw & 3)] = d;
    } else {  // dw in {48,49}: k 192..199
      int g = row / 200, u = row - g * 200;
      Wreg[u * 8 + g * 2 + (dw - 48)] = d;
    }
  }
  if (i < LDG) biasc[i] = (i < G4H) ? (b_ih[i] + b_hh[i]) : 0.f;
}

// ---------------- bf16 MFMA GEMM: C[M,N] = A[M,K] * B[N,K]^T (+epilogue) ----------------
// 1D grid + chunked XCD swizzle (T1, m157): logical id = (bid&7)*(nwg/8)+(bid>>3).
enum { EPI_GATES = 0, EPI_H1 = 1, EPI_H2 = 2, EPI_OUT = 3 };

__device__ __forceinline__ f32x4 mfma16(bf16x8 a, bf16x8 b, f32x4 c) {
  return __builtin_amdgcn_mfma_f32_16x16x32_bf16(a, b, c, 0, 0, 0);
}

template<bool AF32, int EPI>
__global__ __launch_bounds__(256) void gemm_bf16(
    const void* __restrict__ Ap, const u16* __restrict__ Bp,
    void* __restrict__ Cp, int K, int ldc, const float* __restrict__ bias, int nx) {
  __shared__ __attribute__((aligned(16))) char AsRaw[AF32 ? 128 * 32 * 4 : 128 * 32 * 2];
  __shared__ __attribute__((aligned(16))) u16 Bs[128 * 32];
  float* Asf = (float*)AsRaw;
  u16* As16 = (u16*)AsRaw;

  const int t = threadIdx.x;
  const int nwg = gridDim.x;
  const int bid = blockIdx.x;
  const int lid = (bid & 7) * (nwg >> 3) + (bid >> 3);   // chunked XCD swizzle
  const int tileN = (lid % nx) * 128;
  const int tileM = (lid / nx) * 128;
  const int l = t & 63;
  const int w = t >> 6;
  const int wr = (w >> 1) * 64;
  const int wc = (w & 1) * 64;
  const int fr = l & 15;
  const int fg = l >> 4;

  const u16* bsrc[2];
  u16* bdst[2];
#pragma unroll
  for (int j = 0; j < 2; ++j) {
    int tb = w * 1024 + j * 4096 + (t & 63) * 16;
    int row = tb >> 6, gd = (tb >> 4) & 3;
    bsrc[j] = Bp + (size_t)(tileN + row) * K + ((gd ^ ((row >> 1) & 3)) << 3);
    bdst[j] = Bs + w * 512 + j * 2048;
  }
  const float* asrcF[4];
  float* adstF[4];
  const u16* asrcH[2];
  u16* adstH[2];
  if constexpr (AF32) {
#pragma unroll
    for (int j = 0; j < 4; ++j) {
      int tb = w * 1024 + j * 4096 + (t & 63) * 16;
      int row = tb >> 7, gd = (tb >> 4) & 7;
      asrcF[j] = (const float*)Ap + (size_t)(tileM + row) * K + ((gd ^ (row & 7)) << 2);
      adstF[j] = Asf + w * 256 + j * 1024;
    }
  } else {
#pragma unroll
    for (int j = 0; j < 2; ++j) {
      int tb = w * 1024 + j * 4096 + (t & 63) * 16;
      int row = tb >> 6, gd = (tb >> 4) & 3;
      asrcH[j] = (const u16*)Ap + (size_t)(tileM + row) * K + ((gd ^ ((row >> 1) & 3)) << 3);
      adstH[j] = As16 + w * 512 + j * 2048;
    }
  }

  f32x4 acc[4][4];
#pragma unroll
  for (int m = 0; m < 4; ++m)
#pragma unroll
    for (int n = 0; n < 4; ++n) {
      f32x4 z = {0.f, 0.f, 0.f, 0.f};
      acc[m][n] = z;
    }

  for (int k0 = 0; k0 < K; k0 += 32) {
#pragma unroll
    for (int j = 0; j < 2; ++j) { gl16(bsrc[j], bdst[j]); bsrc[j] += 32; }
    if constexpr (AF32) {
#pragma unroll
      for (int j = 0; j < 4; ++j) { gl16(asrcF[j], adstF[j]); asrcF[j] += 32; }
    } else {
#pragma unroll
      for (int j = 0; j < 2; ++j) { gl16(asrcH[j], adstH[j]); asrcH[j] += 32; }
    }
    __syncthreads();

    bf16x8 av[4], bv[4];
#pragma unroll
    for (int m = 0; m < 4; ++m) {
      const int row = wr + m * 16 + fr;
      if constexpr (AF32) {
        const int g0 = (2 * fg) ^ (row & 7);
        const int g1 = (2 * fg + 1) ^ (row & 7);
        float4 p0 = *(const float4*)(Asf + row * 32 + g0 * 4);
        float4 p1 = *(const float4*)(Asf + row * 32 + g1 * 4);
        uint4 u;
        u.x = cvtpk(p0.x, p0.y); u.y = cvtpk(p0.z, p0.w);
        u.z = cvtpk(p1.x, p1.y); u.w = cvtpk(p1.z, p1.w);
        av[m] = __builtin_bit_cast(bf16x8, u);
      } else {
        const int g = fg ^ ((row >> 1) & 3);
        av[m] = __builtin_bit_cast(bf16x8, *(const u16x8*)(As16 + row * 32 + g * 8));
      }
    }
#pragma unroll
    for (int n = 0; n < 4; ++n) {
      const int row = wc + n * 16 + fr;
      const int g = fg ^ ((row >> 1) & 3);
      bv[n] = __builtin_bit_cast(bf16x8, *(const u16x8*)(Bs + row * 32 + g * 8));
    }
#pragma unroll
    for (int m = 0; m < 4; ++m)
#pragma unroll
      for (int n = 0; n < 4; ++n)
        acc[m][n] = mfma16(av[m], bv[n], acc[m][n]);
    __syncthreads();
  }

#pragma unroll
  for (int m = 0; m < 4; ++m) {
#pragma unroll
    for (int n = 0; n < 4; ++n) {
      const int gcol = tileN + wc + n * 16 + fr;
      const int growb = tileM + wr + m * 16 + fg * 4;
#pragma unroll
      for (int r = 0; r < 4; ++r) {
        const int grow = growb + r;
        float v = acc[m][n][r];
        if constexpr (EPI == EPI_GATES) {
          v += bias[gcol];   // b_ih + b_hh folded here
          ((u16*)Cp)[(size_t)grow * ldc + gcol] = f2b(v);
        } else if constexpr (EPI == EPI_H1) {
          v += bias[(grow >> 7) * 256 + gcol];
          v = fmaxf(v, 0.f);
          ((u16*)Cp)[(size_t)grow * ldc + gcol] = f2b(v);
        } else if constexpr (EPI == EPI_H2) {
          v += bias[gcol];
          v = fmaxf(v, 0.f);
          ((u16*)Cp)[(size_t)grow * ldc + gcol] = f2b(v);
        } else {
          v += bias[gcol];
          ((float*)Cp)[(size_t)grow * ldc + gcol] = sigf(v);
        }
      }
    }
  }
}

// ---------------- fused LSTM scan + encoder + VQ + p1 ----------------
// 640 threads (10 waves), one block per batch. W_hh i8 in LDS ([jb][row]
// uint4) + tail dwords in kh2 regs. 3-way k-split (R16/R17 structure,
// measured 222us): kh1/kh2 write uint4 partials; kh0 adds + activation
// (worker-local) + h-write. lgkmcnt-only barriers keep gate prefetch in
// flight. Best verified configuration (477.6us total).
__global__ __launch_bounds__(NTHR) void lstm_enc(
    const u16* __restrict__ gates, const uint4* __restrict__ W4g,
    const uint4* __restrict__ WregG,
    const float* __restrict__ Wenc, const float* __restrict__ b_enc,
    const float* __restrict__ emb, const float* __restrict__ W1,
    const float* __restrict__ b1, const float* __restrict__ noise,
    float* __restrict__ p1) {
  extern __shared__ __attribute__((aligned(16))) char dynsm[];
  uint4* W4 = (uint4*)dynsm;                       // [12*800] uint4 (i8)
  __shared__ __attribute__((aligned(16))) unsigned sh_hq[2][56];  // h i8, dbuf, pad 0
  __shared__ __attribute__((aligned(16))) char sh_un[2 * 208 * 16];  // sh_p / rd+ri
  __shared__ __attribute__((aligned(16))) float sh_hf[HID];
  __shared__ __attribute__((aligned(16))) float sh_ze[LATENT];
  __shared__ float sh_zq[LATENT];
  int (*sh_p)[208][4] = (int(*)[208][4])sh_un;   // [2][208][4]
  float* sh_rd = (float*)sh_un;                  // [640]
  int* sh_ri = (int*)(sh_un + NTHR * 4);         // [640]
  const int r = threadIdx.x;
  const int b = blockIdx.x;
  const bool act = (r < 600);
  const int kh = r / 200;          // 0,1,2 (3 for idle tail)
  const int u = r - kh * 200;
  const bool lo = (kh == 0);

  // stage W4 into LDS (9600 uint4, coalesced; L2-resident source)
  for (int i = r; i < W4_UINT4; i += NTHR) W4[i] = W4g[i];
  uint4 wt0 = {0, 0, 0, 0}, wt1 = {0, 0, 0, 0};
  if (kh == 2) { wt0 = WregG[u * 2]; wt1 = WregG[u * 2 + 1]; }
  if (r < 56) { sh_hq[0][r] = 0; sh_hq[1][r] = 0; }
  float c = 0.f, hlast = 0.f;
  const u16* gp = gates + (size_t)b * TLEN * LDG + u;
  float gv0 = 0.f, gv1 = 0.f, gv2 = 0.f, gv3 = 0.f;
  if (lo) {
    gv0 = b2f(gp[0]); gv1 = b2f(gp[200]);
    gv2 = b2f(gp[400]); gv3 = b2f(gp[600]);
  }
  __syncthreads();   // full drain: W4 staging (global_load_lds) resident

  for (int t = 0; t < TLEN; ++t) {
    gp += LDG;
    float gn0 = 0.f, gn1 = 0.f, gn2 = 0.f, gn3 = 0.f;
    if (lo && t + 1 < TLEN) {
      gn0 = b2f(gp[0]); gn1 = b2f(gp[200]);
      gn2 = b2f(gp[400]); gn3 = b2f(gp[600]);
    }
    const int cur = t & 1, nxt = cur ^ 1;

    int a0 = 0, a1 = 0, a2 = 0, a3 = 0;
    if (act) {
      unsigned hd[16];
#pragma unroll
      for (int j = 0; j < 4; ++j) {
        uint4 v = ((const uint4*)sh_hq[cur])[kh * 4 + j];
        hd[4 * j + 0] = v.x; hd[4 * j + 1] = v.y;
        hd[4 * j + 2] = v.z; hd[4 * j + 3] = v.w;
      }
#pragma unroll
      for (int j = 0; j < 4; ++j) {
        const int jb = kh * 4 + j;
        uint4 w0 = W4[jb * 800 + u];
        uint4 w1 = W4[jb * 800 + 200 + u];
        uint4 w2 = W4[jb * 800 + 400 + u];
        uint4 w3 = W4[jb * 800 + 600 + u];
#pragma unroll
        for (int e = 0; e < 4; ++e) {
          unsigned h = hd[j * 4 + e];
          a0 = dot4((&w0.x)[e], h, a0);
          a1 = dot4((&w1.x)[e], h, a1);
          a2 = dot4((&w2.x)[e], h, a2);
          a3 = dot4((&w3.x)[e], h, a3);
        }
      }
      if (kh == 2) {
        // tail k 192..199 from registers
        uint2 ht = *(const uint2*)&sh_hq[cur][48];
        a0 = dot4(wt0.x, ht.x, a0); a0 = dot4(wt0.y, ht.y, a0);
        a1 = dot4(wt0.z, ht.x, a1); a1 = dot4(wt0.w, ht.y, a1);
        a2 = dot4(wt1.x, ht.x, a2); a2 = dot4(wt1.y, ht.y, a2);
        a3 = dot4(wt1.z, ht.x, a3); a3 = dot4(wt1.w, ht.y, a3);
      }
      if (kh) {
        int4 pv; pv.x = a0; pv.y = a1; pv.z = a2; pv.w = a3;
        *(int4*)&sh_p[kh - 1][u][0] = pv;
      }
    }
    bar_lds();   // partials visible; gate prefetch stays in flight
    if (lo) {
      int4 p0 = *(const int4*)&sh_p[0][u][0];
      int4 p1v = *(const int4*)&sh_p[1][u][0];
      float gi = gv0 + (float)(a0 + p0.x + p1v.x) * ISCL;
      float gf = gv1 + (float)(a1 + p0.y + p1v.y) * ISCL;
      float gg = gv2 + (float)(a2 + p0.z + p1v.z) * ISCL;
      float go = gv3 + (float)(a3 + p0.w + p1v.w) * ISCL;
      c = sigf(gf) * c + sigf(gi) * tanh_fast(gg);
      hlast = sigf(go) * tanh_fast(c);
      ((char*)sh_hq[nxt])[u] = (char)__float2int_rn(hlast * HSCL);
    }
    bar_lds();   // h(t+1) visible; sh_p free for reuse
    gv0 = gn0; gv1 = gn1; gv2 = gn2; gv3 = gn3;
  }

  if (lo) sh_hf[u] = hlast;
  __syncthreads();

  // encoder: z_e = h @ Wenc^T + b_enc
  if (r < LATENT) {
    float z = b_enc[r];
#pragma unroll 4
    for (int k = 0; k < HID; ++k) z = fmaf(Wenc[(size_t)r * HID + k], sh_hf[k], z);
    sh_ze[r] = z;
  }
  __syncthreads();

  // VQ: argmin_k ||e_k||^2 - 2 z_e . e_k
  float best = INFINITY; int bi = 0;
  for (int k = r; k < NCODES; k += NTHR) {
    float d = 0.f;
#pragma unroll
    for (int q = 0; q < LATENT / 4; ++q) {
      float4 e = *(const float4*)&emb[(size_t)k * LATENT + q * 4];
      float4 z = *(const float4*)&sh_ze[q * 4];
      d += e.x * (e.x - 2.f * z.x) + e.y * (e.y - 2.f * z.y)
         + e.z * (e.z - 2.f * z.z) + e.w * (e.w - 2.f * z.w);
    }
    if (d < best) { best = d; bi = k; }
  }
  sh_rd[r] = best; sh_ri[r] = bi;
  __syncthreads();
  for (int s = 512; s > 0; s >>= 1) {
    if (r < s && r + s < NTHR) {
      float od = sh_rd[r + s]; int oi = sh_ri[r + s];
      if (od < sh_rd[r] || (od == sh_rd[r] && oi < sh_ri[r])) { sh_rd[r] = od; sh_ri[r] = oi; }
    }
    __syncthreads();
  }
  const int kmin = sh_ri[0];
  if (r < LATENT) sh_zq[r] = emb[(size_t)kmin * LATENT + r];
  __syncthreads();

  // p1[b][j] = b1 + W1[:,0:128].zq + W1[:,1664:2432].noise  (pad cols 200..255 = 0)
  if (r < 256) {
    float v = 0.f;
    if (r < HID) {
      v = b1[r];
      const float* wrow = W1 + (size_t)r * 2432;
#pragma unroll 4
      for (int d = 0; d < LATENT; ++d) v = fmaf(wrow[d], sh_zq[d], v);
      const float* nz = noise + (size_t)b * DIN;
#pragma unroll 4
      for (int d = 0; d < DIN; ++d) v = fmaf(wrow[1664 + d], nz[d], v);
    }
    p1[b * 256 + r] = v;
  }
}

// ---------------- host ----------------
extern "C" void kernel_launch(void* const* d_in, const int* in_sizes, int n_in,
                              void* d_out, int out_size, void* d_ws, size_t ws_size,
                              hipStream_t stream) {
  const float* x     = (const float*)d_in[0];
  const float* cond  = (const float*)d_in[1];
  const float* noise = (const float*)d_in[2];
  const float* W_ih  = (const float*)d_in[3];
  const float* W_hh  = (const float*)d_in[4];
  const float* b_ih  = (const float*)d_in[5];
  const float* b_hh  = (const float*)d_in[6];
  const float* W_enc = (const float*)d_in[7];
  const float* b_enc = (const float*)d_in[8];
  const float* emb   = (const float*)d_in[9];
  const float* W1    = (const float*)d_in[10];
  const float* b1    = (const float*)d_in[11];
  const float* W2    = (const float*)d_in[12];
  const float* b2    = (const float*)d_in[13];
  const float* W3    = (const float*)d_in[14];
  const float* b3    = (const float*)d_in[15];

  char* ws = (char*)d_ws;
  size_t off = 0;
  auto alloc = [&](size_t bytes) -> void* {
    void* p = ws + off; off += (bytes + 255) & ~(size_t)255; return p;
  };
  u16*      W_ihb = (u16*)alloc((size_t)896 * 768 * 2);
  u16*      W1cb  = (u16*)alloc((size_t)256 * 1536 * 2);
  u16*      W2b   = (u16*)alloc((size_t)512 * 256 * 2);
  u16*      W3b   = (u16*)alloc((size_t)768 * 512 * 2);
  float*    b2p   = (float*)alloc(512 * 4);
  unsigned* W4    = (unsigned*)alloc((size_t)W4_BYTES);
  unsigned* Wreg  = (unsigned*)alloc((size_t)200 * 8 * 4);
  float*    biasc = (float*)alloc(LDG * 4);
  u16*      gates = (u16*)alloc((size_t)MROWS * LDG * 2);
  float*    p1    = (float*)alloc(256 * 256 * 4);
  u16*      h1    = (u16*)alloc((size_t)MROWS * LDH1 * 2);
  u16*      h2    = (u16*)alloc((size_t)MROWS * LDH2 * 2);

  cvt_pad<<<dim3((896 * 768 + 255) / 256), 256, 0, stream>>>(W_ih, W_ihb, 800, 768, 768, 0, 896, 768);
  cvt_pad<<<dim3((256 * 1536 + 255) / 256), 256, 0, stream>>>(W1, W1cb, 200, 1536, 2432, 128, 256, 1536);
  cvt_pad<<<dim3((512 * 256 + 255) / 256), 256, 0, stream>>>(W2, W2b, 400, 200, 200, 0, 512, 256);
  cvt_pad<<<dim3((768 * 512 + 255) / 256), 256, 0, stream>>>(W3, W3b, 768, 400, 400, 0, 768, 512);
  pad_f32<<<dim3(2), 256, 0, stream>>>(b2, b2p, 400, 512);
  pack_whh_i8<<<dim3((800 * 50 + 255) / 256), 256, 0, stream>>>(W_hh, W4, Wreg, b_ih, b_hh, biasc);

  // gates = x @ W_ih^T + (b_ih + b_hh), bf16 out, ld 896  (1792 blocks, %8==0)
  gemm_bf16<true, EPI_GATES><<<dim3((LDG / 128) * (MROWS / 128)), 256, 0, stream>>>(
      x, W_ihb, gates, 768, LDG, biasc, LDG / 128);

  // LSTM scan + encoder + VQ + p1 (W_hh in dynamic LDS, i8; 640 thr, 3-way k-split)
  static bool attr_set = false;
  if (!attr_set) {
    (void)hipFuncSetAttribute((const void*)lstm_enc,
                              hipFuncAttributeMaxDynamicSharedMemorySize, W4_BYTES);
    attr_set = true;
  }
  lstm_enc<<<dim3(NB), NTHR, W4_BYTES, stream>>>(gates, (const uint4*)W4, (const uint4*)Wreg,
                                                 W_enc, b_enc, emb, W1, b1, noise, p1);

  // h1 = relu(cond @ W1c^T + p1[b])   (512 blocks)
  gemm_bf16<true, EPI_H1><<<dim3((LDH1 / 128) * (MROWS / 128)), 256, 0, stream>>>(
      cond, W1cb, h1, DCOND, LDH1, p1, LDH1 / 128);
  // h2 = relu(h1 @ W2^T + b2)   (1024 blocks)
  gemm_bf16<false, EPI_H2><<<dim3((LDH2 / 128) * (MROWS / 128)), 256, 0, stream>>>(
      h1, W2b, h2, LDH1, LDH2, b2p, LDH2 / 128);
  // out = sigmoid(h2 @ W3^T + b3)   (1536 blocks)
  gemm_bf16<false, EPI_OUT><<<dim3((NOUT / 128) * (MROWS / 128)), 256, 0, stream>>>(
      h2, W3b, (float*)d_out, LDH2, NOUT, b3, NOUT / 128);
}